// Round 7
// baseline (90.461 us; speedup 1.0000x reference)
//
#include <hip/hip_runtime.h>

#define BS 8192
#define D  128
#define TI 256              // i-rows per block (4 waves x 64 rows)
#define JCHUNK 512          // j's per block chunk
#define NJC (BS / JCHUNK)   // 16
#define NP 16               // panels per chunk (32 j-rows, f32 = 16 KB)
#define PANB (32 * D * 4)   // 16384 bytes per panel (f32 rows)
#define NBLK (BS / TI * NJC)      // 512 blocks, 1-D grid

typedef __bf16 bf16x8 __attribute__((ext_vector_type(8)));
typedef float  f32x16 __attribute__((ext_vector_type(16)));

// async global->LDS, 16B per lane: LDS dest = (wave-uniform base) + lane*16,
// global src is per-lane (m97/m104 pattern, verified R3-R6)
__device__ __forceinline__ void gload_lds16(const void* g, void* l)
{
    __builtin_amdgcn_global_load_lds(
        (const __attribute__((address_space(1))) void*)g,
        (__attribute__((address_space(3))) void*)l, 16, 0, 0);
}

#define WAITVM(n) asm volatile("s_waitcnt vmcnt(" #n ")" ::: "memory")

// ---------------------------------------------------------------------------
// stats: fp32 row reductions only (a_sq, psn = -p_sq/2, pd2). The packed
// Apack/Ppack intermediates are GONE (R7): max_kernel now converts f32->bf16
// in-register from the read-only feats input, eliminating the 12.6 MB dirty
// workspace round-trip + inter-dispatch flush that every max-operand read
// paid for (R6 cold-dispatch counters: 128 us, MfmaUtil 2.6%).
// ---------------------------------------------------------------------------
__global__ __launch_bounds__(256) void stats_kernel(
        const float* __restrict__ feats, float* __restrict__ a_sq,
        float* __restrict__ psn, float* __restrict__ pd2)
{
    const int tile = blockIdx.x;          // 0..255
    const int tid  = threadIdx.x;
    const int r    = tid >> 3;            // row within tile, 0..31
    const int kb   = tid & 7;             // 16-float chunk, 0..7
    const int row  = tile * 32 + r;

    const float4* asrc = (const float4*)(feats + (size_t)row * D + kb * 16);
    const float4* psrc = (const float4*)(feats + (size_t)(row + BS) * D + kb * 16);
    float4 a0 = asrc[0], a1 = asrc[1], a2 = asrc[2], a3 = asrc[3];
    float4 p0 = psrc[0], p1 = psrc[1], p2 = psrc[2], p3 = psrc[3];

    float sa = a0.x*a0.x + a0.y*a0.y + a0.z*a0.z + a0.w*a0.w
             + a1.x*a1.x + a1.y*a1.y + a1.z*a1.z + a1.w*a1.w
             + a2.x*a2.x + a2.y*a2.y + a2.z*a2.z + a2.w*a2.w
             + a3.x*a3.x + a3.y*a3.y + a3.z*a3.z + a3.w*a3.w;
    float sp = p0.x*p0.x + p0.y*p0.y + p0.z*p0.z + p0.w*p0.w
             + p1.x*p1.x + p1.y*p1.y + p1.z*p1.z + p1.w*p1.w
             + p2.x*p2.x + p2.y*p2.y + p2.z*p2.z + p2.w*p2.w
             + p3.x*p3.x + p3.y*p3.y + p3.z*p3.z + p3.w*p3.w;
    float d;
    float sd = 0.0f;
    d = a0.x-p0.x; sd += d*d;  d = a0.y-p0.y; sd += d*d;
    d = a0.z-p0.z; sd += d*d;  d = a0.w-p0.w; sd += d*d;
    d = a1.x-p1.x; sd += d*d;  d = a1.y-p1.y; sd += d*d;
    d = a1.z-p1.z; sd += d*d;  d = a1.w-p1.w; sd += d*d;
    d = a2.x-p2.x; sd += d*d;  d = a2.y-p2.y; sd += d*d;
    d = a2.z-p2.z; sd += d*d;  d = a2.w-p2.w; sd += d*d;
    d = a3.x-p3.x; sd += d*d;  d = a3.y-p3.y; sd += d*d;
    d = a3.z-p3.z; sd += d*d;  d = a3.w-p3.w; sd += d*d;

    #pragma unroll
    for (int off = 1; off <= 4; off <<= 1) {
        sa += __shfl_xor(sa, off, 64);
        sp += __shfl_xor(sp, off, 64);
        sd += __shfl_xor(sd, off, 64);
    }
    if (kb == 0) { a_sq[row] = sa; psn[row] = -0.5f * sp; pd2[row] = sd; }
}

// ---------------------------------------------------------------------------
// max kernel, R7: operands straight from read-only feats.
//
//  - A fragments: prologue converts the wave's 64 anchor rows f32->bf16 in
//    registers. Mapping identical to the verified pack layout: lane holds
//    A[row = base + (lane&31)][k = s*16 + (lane>>5)*8 .. +8].
//  - B panels: 32 positive rows = contiguous 16 KB of feats (f32), staged
//    via the counted-vmcnt 4-buffer gload_lds pipeline (depth 3, one
//    s_barrier per panel, vmcnt never 0 until the tail). f32->bf16 cvt
//    happens at fragment-read time (compiler emits cvt_pk pairs).
//  - LDS swizzle: linear [row][k] f32 rows would 32-way bank-conflict
//    (512 B stride). Store 16-B chunk c of row r at slot (c ^ r); applied
//    by pre-swizzling the per-lane GLOBAL src (LDS dest stays linear, as
//    gload_lds requires); reads apply the same XOR. Conflict-free.
//  - 2-D XCD clustering: xcd = b&7 owns an 8 i-block x 8 j-chunk tile;
//    per-XCD working set = 1 MB anchors + 2 MB positives < 4 MB L2.
//
// mfma_f32_32x32x16_bf16 C/D layout (HW-verified, learn_hip m74/m101):
//   col = lane&31, row = (reg&3) + 8*(reg>>2) + 4*(lane>>5)
// ---------------------------------------------------------------------------
__global__ __launch_bounds__(256, 2) void max_kernel(
        const float* __restrict__ feats, const float* __restrict__ psn,
        float* __restrict__ partmax)
{
    __shared__ __align__(16) char sB[4 * PANB];   // 64 KB, 4 panel bufs

    const int tid  = threadIdx.x;               // 0..255
    const int wave = tid >> 6;                  // 0..3
    const int lane = tid & 63;
    const int l31  = lane & 31;
    const int half = lane >> 5;

    // 2-D XCD clustering (bijective over 512 blocks):
    //   xcd k = b&7 owns i-blocks [(k&3)*8, +8) x j-chunks [(k>>2)*8, +8)
    const int b   = blockIdx.x;
    const int k8  = b & 7;
    const int w   = b >> 3;                     // 0..63
    const int bi  = (k8 & 3) * 8 + (w & 7);     // i-block 0..31
    const int by  = (k8 >> 2) * 8 + (w >> 3);   // j-chunk 0..15

    const int i0    = bi * TI + wave * 64;      // wave's 64 anchor rows
    const int jbase = by * JCHUNK;

    // A fragments (2 tiles/wave) converted f32->bf16 in registers.
    bf16x8 afA[8], afB[8];
    #pragma unroll
    for (int s = 0; s < 8; ++s) {
        const float* pa = feats + (size_t)(i0 + l31) * D + s * 16 + half * 8;
        const float* pb = feats + (size_t)(i0 + 32 + l31) * D + s * 16 + half * 8;
        float4 u0 = ((const float4*)pa)[0], u1 = ((const float4*)pa)[1];
        float4 v0 = ((const float4*)pb)[0], v1 = ((const float4*)pb)[1];
        bf16x8 fa, fb;
        fa[0]=(__bf16)u0.x; fa[1]=(__bf16)u0.y; fa[2]=(__bf16)u0.z; fa[3]=(__bf16)u0.w;
        fa[4]=(__bf16)u1.x; fa[5]=(__bf16)u1.y; fa[6]=(__bf16)u1.z; fa[7]=(__bf16)u1.w;
        fb[0]=(__bf16)v0.x; fb[1]=(__bf16)v0.y; fb[2]=(__bf16)v0.z; fb[3]=(__bf16)v0.w;
        fb[4]=(__bf16)v1.x; fb[5]=(__bf16)v1.y; fb[6]=(__bf16)v1.z; fb[7]=(__bf16)v1.w;
        afA[s] = fa; afB[s] = fb;
    }

    // acc-init constants for all 16 j-tiles of this chunk
    float ci[16];
    #pragma unroll
    for (int k = 0; k < 16; ++k) ci[k] = psn[jbase + k * 32 + l31];

    // drain prologue loads so in-loop vmcnt counts are exact gload counts
    WAITVM(0);
    __builtin_amdgcn_sched_barrier(0);

    float rmaxA[16], rmaxB[16];
    #pragma unroll
    for (int r = 0; r < 16; ++r) { rmaxA[r] = -3.0e38f; rmaxB[r] = -3.0e38f; }

    // B panel staging: panel p = positive rows [jbase+p*32, +32) = 16 KB
    // contiguous f32. Wave stages rows wave*8..+8 (4 KB) as 4 gloads.
    // Pre-swizzled per-lane src: slot m = q*64+lane holds row R = wave*8 +
    // q*2 + half, chunk cg = l31 ^ R  (store key = row, matches read key).
    const char* gB = (const char*)(feats + (size_t)BS * D) + (size_t)jbase * 512;
    int sof[4];
    #pragma unroll
    for (int q = 0; q < 4; ++q) {
        const int R = wave * 8 + q * 2 + half;
        sof[q] = R * 512 + ((l31 ^ R) << 4);
    }

    #define STAGE(p)                                                       \
        do {                                                               \
            const char* g_ = gB + (size_t)(p) * PANB;                      \
            char* l_ = sB + ((p) & 3) * PANB + wave * 4096;                \
            gload_lds16(g_ + sof[0], l_);                                  \
            gload_lds16(g_ + sof[1], l_ + 1024);                           \
            gload_lds16(g_ + sof[2], l_ + 2048);                           \
            gload_lds16(g_ + sof[3], l_ + 3072);                           \
        } while (0)

    // prologue: panels 0..2 in flight (depth 3)
    STAGE(0);
    STAGE(1);
    STAGE(2);

    const int rowb = l31 * 512;                 // lane's j-row base in panel

    #pragma unroll
    for (int t = 0; t < NP; ++t) {
        // drain panel t only; deeper panels stay in flight across barrier
        if (t <= NP - 3)      WAITVM(8);
        else if (t == NP - 2) WAITVM(4);
        else                  WAITVM(0);
        __builtin_amdgcn_sched_barrier(0);
        __builtin_amdgcn_s_barrier();
        __builtin_amdgcn_sched_barrier(0);

        // stage AFTER the barrier: overwrites buf (t-1)&3, fully consumed
        // before barrier(t) on every wave. Race-free 4-buffer ring.
        if (t + 3 < NP) STAGE(t + 3);

        const char* pb = sB + (t & 3) * PANB;
        const float cv = ci[t];
        f32x16 acc0, acc1;
        #pragma unroll
        for (int r = 0; r < 16; ++r) { acc0[r] = cv; acc1[r] = cv; }

        __builtin_amdgcn_s_setprio(1);
        #pragma unroll
        for (int s = 0; s < 8; ++s) {
            const int c0 = s * 4 + half * 2;    // linear 16B chunk of row
            float4 r0 = *(const float4*)(pb + rowb + (((c0    ) ^ l31) << 4));
            float4 r1 = *(const float4*)(pb + rowb + (((c0 + 1) ^ l31) << 4));
            bf16x8 bb;
            bb[0]=(__bf16)r0.x; bb[1]=(__bf16)r0.y; bb[2]=(__bf16)r0.z; bb[3]=(__bf16)r0.w;
            bb[4]=(__bf16)r1.x; bb[5]=(__bf16)r1.y; bb[6]=(__bf16)r1.z; bb[7]=(__bf16)r1.w;
            acc0 = __builtin_amdgcn_mfma_f32_32x32x16_bf16(afA[s], bb,
                                                           acc0, 0, 0, 0);
            acc1 = __builtin_amdgcn_mfma_f32_32x32x16_bf16(afB[s], bb,
                                                           acc1, 0, 0, 0);
        }
        __builtin_amdgcn_s_setprio(0);

        #pragma unroll
        for (int r = 0; r < 16; ++r) {
            rmaxA[r] = fmaxf(rmaxA[r], acc0[r]);
            rmaxB[r] = fmaxf(rmaxB[r], acc1[r]);
        }
    }
    #undef STAGE

    // max across the 32 columns (off<=16 stays within each 32-lane half)
    #pragma unroll
    for (int r = 0; r < 16; ++r) {
        float vA = rmaxA[r], vB = rmaxB[r];
        #pragma unroll
        for (int off = 1; off <= 16; off <<= 1) {
            vA = fmaxf(vA, __shfl_xor(vA, off, 64));
            vB = fmaxf(vB, __shfl_xor(vB, off, 64));
        }
        rmaxA[r] = vA; rmaxB[r] = vB;
    }
    if (l31 == 0) {
        float* dst = partmax + (size_t)by * BS + i0;
        #pragma unroll
        for (int r = 0; r < 16; ++r) {
            int row = (r & 3) + 8 * (r >> 2) + 4 * half;
            dst[row]      = rmaxA[r];
            dst[row + 32] = rmaxB[r];
        }
    }
}

// ---------------------------------------------------------------------------
// fin stage 1: 32 blocks x 256 threads; thread handles exactly one i.
// min_j d2 = a_sq[i] - 2 * max_c partmax[c][i]
// ---------------------------------------------------------------------------
__global__ __launch_bounds__(256) void fin1_kernel(
        const float* __restrict__ partmax, const float* __restrict__ a_sq,
        const float* __restrict__ pd2, float* __restrict__ bsum)
{
    __shared__ float ssum[4];
    const int t = threadIdx.x;
    const int i = blockIdx.x * 256 + t;

    float m = -3.0e38f;
    #pragma unroll
    for (int c = 0; c < NJC; ++c)
        m = fmaxf(m, partmax[c * BS + i]);
    float negd = sqrtf(fmaxf(fmaf(-2.0f, m, a_sq[i]), 0.0f));
    float posd = sqrtf(pd2[i]);
    float sum = fmaxf(posd - negd + 1.0f, 0.0f);

    #pragma unroll
    for (int off = 32; off >= 1; off >>= 1) sum += __shfl_xor(sum, off, 64);
    if ((t & 63) == 0) ssum[t >> 6] = sum;
    __syncthreads();
    if (t == 0)
        bsum[blockIdx.x] = ssum[0] + ssum[1] + ssum[2] + ssum[3];
}

// fin stage 2: one wave sums the 32 block partials.
__global__ __launch_bounds__(64) void fin2_kernel(
        const float* __restrict__ bsum, float* __restrict__ out)
{
    const int t = threadIdx.x;
    float v = (t < 32) ? bsum[t] : 0.0f;
    #pragma unroll
    for (int off = 32; off >= 1; off >>= 1) v += __shfl_xor(v, off, 64);
    if (t == 0) out[0] = v / (float)BS;
}

// ---------------------------------------------------------------------------
extern "C" void kernel_launch(void* const* d_in, const int* in_sizes, int n_in,
                              void* d_out, int out_size, void* d_ws,
                              size_t ws_size, hipStream_t stream)
{
    const float* feats = (const float*)d_in[0];

    char* ws = (char*)d_ws;
    float* a_sq   = (float*)ws;   ws += (size_t)BS * 4;
    float* psn    = (float*)ws;   ws += (size_t)BS * 4;
    float* pd2    = (float*)ws;   ws += (size_t)BS * 4;
    float* partmax = (float*)ws;  ws += (size_t)NJC * BS * 4; // 512 KB
    float* bsum   = (float*)ws;   ws += 32 * 4;

    stats_kernel<<<BS / 32, 256, 0, stream>>>(feats, a_sq, psn, pd2);
    max_kernel<<<NBLK, 256, 0, stream>>>(feats, psn, partmax);
    fin1_kernel<<<BS / 256, 256, 0, stream>>>(partmax, a_sq, pd2, bsum);
    fin2_kernel<<<1, 64, 0, stream>>>(bsum, (float*)d_out);
}

// Round 8
// 81.560 us; speedup vs baseline: 1.1091x; 1.1091x over previous
//
#include <hip/hip_runtime.h>

#define BS 8192
#define D  128
#define TI 512              // i-rows per block (8 waves x 64 rows)
#define JCHUNK 512          // j's per block (ENTIRE chunk LDS-resident)
#define NJC (BS / JCHUNK)   // 16
#define NBI (BS / TI)       // 16 i-blocks
#define NBLK (NBI * NJC)    // 256 blocks = 1 per CU

typedef __bf16 bf16x8 __attribute__((ext_vector_type(8)));
typedef float  f32x16 __attribute__((ext_vector_type(16)));

// async global->LDS, 16B per lane: LDS dest = (wave-uniform base) + lane*16,
// global src is per-lane (m97/m104 pattern, verified R3-R6)
__device__ __forceinline__ void gload_lds16(const void* g, void* l)
{
    __builtin_amdgcn_global_load_lds(
        (const __attribute__((address_space(1))) void*)g,
        (__attribute__((address_space(3))) void*)l, 16, 0, 0);
}

#define WAITVM(n) asm volatile("s_waitcnt vmcnt(" #n ")" ::: "memory")

// ---------------------------------------------------------------------------
// pack: feats -> fragment-major bf16 for BOTH anchor (Apack) and positive
// (Ppack), plus fp32 row reductions (a_sq, psn = -p_sq/2, pd2). Layout
// (verified): piece ((tile*8 + s)*64 + lane) holds the 8 bf16 operand
// elements for MFMA lane `lane` at k-step s of 32-row tile `tile`:
//   row = tile*32 + (lane&31), k = s*16 + (lane>>5)*8 .. +8
// A j-chunk (16 tiles) is a CONTIGUOUS 128 KB block of Ppack.
// (R7 taught: direct-from-feats + in-loop cvt is SLOWER — packed operands
// restored.)
// ---------------------------------------------------------------------------
__global__ __launch_bounds__(256) void pack_kernel(
        const float* __restrict__ feats,
        __bf16* __restrict__ Apack, __bf16* __restrict__ Ppack,
        float* __restrict__ a_sq, float* __restrict__ psn,
        float* __restrict__ pd2)
{
    const int tile = blockIdx.x;          // 0..255
    const int tid  = threadIdx.x;
    const int r    = tid >> 3;            // row within tile, 0..31
    const int kb   = tid & 7;             // k-block = MFMA step s, 0..7
    const int row  = tile * 32 + r;

    const float4* asrc = (const float4*)(feats + (size_t)row * D + kb * 16);
    const float4* psrc = (const float4*)(feats + (size_t)(row + BS) * D + kb * 16);
    float4 a0 = asrc[0], a1 = asrc[1], a2 = asrc[2], a3 = asrc[3];
    float4 p0 = psrc[0], p1 = psrc[1], p2 = psrc[2], p3 = psrc[3];

    bf16x8 alo, ahi, plo, phi;
    alo[0]=(__bf16)a0.x; alo[1]=(__bf16)a0.y; alo[2]=(__bf16)a0.z; alo[3]=(__bf16)a0.w;
    alo[4]=(__bf16)a1.x; alo[5]=(__bf16)a1.y; alo[6]=(__bf16)a1.z; alo[7]=(__bf16)a1.w;
    ahi[0]=(__bf16)a2.x; ahi[1]=(__bf16)a2.y; ahi[2]=(__bf16)a2.z; ahi[3]=(__bf16)a2.w;
    ahi[4]=(__bf16)a3.x; ahi[5]=(__bf16)a3.y; ahi[6]=(__bf16)a3.z; ahi[7]=(__bf16)a3.w;
    plo[0]=(__bf16)p0.x; plo[1]=(__bf16)p0.y; plo[2]=(__bf16)p0.z; plo[3]=(__bf16)p0.w;
    plo[4]=(__bf16)p1.x; plo[5]=(__bf16)p1.y; plo[6]=(__bf16)p1.z; plo[7]=(__bf16)p1.w;
    phi[0]=(__bf16)p2.x; phi[1]=(__bf16)p2.y; phi[2]=(__bf16)p2.z; phi[3]=(__bf16)p2.w;
    phi[4]=(__bf16)p3.x; phi[5]=(__bf16)p3.y; phi[6]=(__bf16)p3.z; phi[7]=(__bf16)p3.w;

    const size_t pb = ((size_t)tile * 8 + kb) * 64;
    ((bf16x8*)Apack)[pb + r]      = alo;
    ((bf16x8*)Apack)[pb + 32 + r] = ahi;
    ((bf16x8*)Ppack)[pb + r]      = plo;
    ((bf16x8*)Ppack)[pb + 32 + r] = phi;

    float sa = a0.x*a0.x + a0.y*a0.y + a0.z*a0.z + a0.w*a0.w
             + a1.x*a1.x + a1.y*a1.y + a1.z*a1.z + a1.w*a1.w
             + a2.x*a2.x + a2.y*a2.y + a2.z*a2.z + a2.w*a2.w
             + a3.x*a3.x + a3.y*a3.y + a3.z*a3.z + a3.w*a3.w;
    float sp = p0.x*p0.x + p0.y*p0.y + p0.z*p0.z + p0.w*p0.w
             + p1.x*p1.x + p1.y*p1.y + p1.z*p1.z + p1.w*p1.w
             + p2.x*p2.x + p2.y*p2.y + p2.z*p2.z + p2.w*p2.w
             + p3.x*p3.x + p3.y*p3.y + p3.z*p3.z + p3.w*p3.w;
    float d;
    float sd = 0.0f;
    d = a0.x-p0.x; sd += d*d;  d = a0.y-p0.y; sd += d*d;
    d = a0.z-p0.z; sd += d*d;  d = a0.w-p0.w; sd += d*d;
    d = a1.x-p1.x; sd += d*d;  d = a1.y-p1.y; sd += d*d;
    d = a1.z-p1.z; sd += d*d;  d = a1.w-p1.w; sd += d*d;
    d = a2.x-p2.x; sd += d*d;  d = a2.y-p2.y; sd += d*d;
    d = a2.z-p2.z; sd += d*d;  d = a2.w-p2.w; sd += d*d;
    d = a3.x-p3.x; sd += d*d;  d = a3.y-p3.y; sd += d*d;
    d = a3.z-p3.z; sd += d*d;  d = a3.w-p3.w; sd += d*d;

    #pragma unroll
    for (int off = 1; off <= 4; off <<= 1) {
        sa += __shfl_xor(sa, off, 64);
        sp += __shfl_xor(sp, off, 64);
        sd += __shfl_xor(sd, off, 64);
    }
    if (kb == 0) { a_sq[row] = sa; psn[row] = -0.5f * sp; pd2[row] = sd; }
}

// ---------------------------------------------------------------------------
// max kernel, R8: ONE stage, ONE barrier, ZERO in-loop sync.
//
// R0-R7 post-mortem: max_kernel is pinned at ~31 us (~9000 cyc of stall
// per panel) across every panel-level pipeline variant — the invariant is
// the 8-16 barrier-separated phases, each re-exposing staging latency to
// a block-wide join with only 2 blocks/CU of cover. The whole j-chunk is
// only 128 KB: it FITS in LDS (160 KB/CU).
//
// Geometry: 256 blocks = exactly 1/CU (16 i-blocks x 16 j-chunks), 512
// threads = 8 waves x 64 i-rows (TI=512, 2 register-resident A-tiles per
// wave, same per-wave profile as R4-R6). The entire 128 KB B-chunk is
// staged in ONE burst (16 x 1 KB gload_lds per wave, ~33 outstanding VMEM
// ops -> cold-miss latency paid once, fully overlapped), then ONE
// __syncthreads, then 16 j-tile bodies of pure ds_read+MFMA+fmax with no
// barriers and no global loads — the compiler can software-pipeline
// ds_reads across bodies freely (m97: its lgkmcnt scheduling is
// near-optimal when not fenced by barriers).
//
// B L2 traffic also halves vs TI=256 (16 i-blocks x 2 MB = 32 MB).
//
// mfma_f32_32x32x16_bf16 C/D layout (HW-verified, learn_hip m74/m101):
//   col = lane&31, row = (reg&3) + 8*(reg>>2) + 4*(lane>>5)
// ---------------------------------------------------------------------------
__global__ __launch_bounds__(512, 2) void max_kernel(
        const __bf16* __restrict__ Apack, const __bf16* __restrict__ Ppack,
        const float* __restrict__ psn, float* __restrict__ partmax)
{
    __shared__ __align__(16) char sB[JCHUNK * D * 2];   // 128 KB: full chunk

    const int tid  = threadIdx.x;               // 0..511
    const int wave = tid >> 6;                  // 0..7
    const int lane = tid & 63;
    const int l31  = lane & 31;
    const int half = lane >> 5;

    const int b  = blockIdx.x;
    const int bi = b & 15;                      // i-block 0..15
    const int by = b >> 4;                      // j-chunk 0..15

    const int i0    = bi * TI + wave * 64;      // wave's 64 anchor rows
    const int itile = i0 >> 5;
    const int jbase = by * JCHUNK;
    const int tile0 = jbase >> 5;

    // --- stage the ENTIRE j-chunk (128 KB) in one burst ---
    // wave w stages bytes [w*16K, +16K): 16 x 1 KB gload_lds, all issued
    // back-to-back (16 outstanding per wave).
    {
        const char* g = (const char*)Ppack + (size_t)tile0 * 8192
                      + wave * 16384 + lane * 16;
        char* l = sB + wave * 16384;
        #pragma unroll
        for (int q = 0; q < 16; ++q)
            gload_lds16(g + q * 1024, l + q * 1024);
    }

    // A fragments (2 tiles/wave) + acc-init constants: issued while the
    // stage burst is in flight (adds ~17 more outstanding VMEM ops).
    bf16x8 afA[8], afB[8];
    {
        const bf16x8* ap = (const bf16x8*)Apack;
        #pragma unroll
        for (int s = 0; s < 8; ++s) {
            afA[s] = ap[((size_t)itile * 8 + s) * 64 + lane];
            afB[s] = ap[((size_t)(itile + 1) * 8 + s) * 64 + lane];
        }
    }
    float ci[16];
    #pragma unroll
    for (int k = 0; k < 16; ++k) ci[k] = psn[jbase + k * 32 + l31];

    float rmaxA[16], rmaxB[16];
    #pragma unroll
    for (int r = 0; r < 16; ++r) { rmaxA[r] = -3.0e38f; rmaxB[r] = -3.0e38f; }

    __syncthreads();                            // the ONLY barrier: full
                                                // vmcnt drain + join

    // --- 16 j-tile bodies: pure LDS + MFMA + fmax, no sync, no gloads ---
    #pragma unroll
    for (int jt = 0; jt < 16; ++jt) {
        const bf16x8* lp = (const bf16x8*)(sB + jt * 8192 + (size_t)lane * 16);
        bf16x8 bb[8];
        #pragma unroll
        for (int s = 0; s < 8; ++s) bb[s] = lp[s * 64];

        const float cv = ci[jt];
        f32x16 acc0, acc1;
        #pragma unroll
        for (int r = 0; r < 16; ++r) { acc0[r] = cv; acc1[r] = cv; }

        __builtin_amdgcn_s_setprio(1);
        #pragma unroll
        for (int s = 0; s < 8; ++s) {
            acc0 = __builtin_amdgcn_mfma_f32_32x32x16_bf16(afA[s], bb[s],
                                                           acc0, 0, 0, 0);
            acc1 = __builtin_amdgcn_mfma_f32_32x32x16_bf16(afB[s], bb[s],
                                                           acc1, 0, 0, 0);
        }
        __builtin_amdgcn_s_setprio(0);

        #pragma unroll
        for (int r = 0; r < 16; ++r) {
            rmaxA[r] = fmaxf(rmaxA[r], acc0[r]);
            rmaxB[r] = fmaxf(rmaxB[r], acc1[r]);
        }
    }

    // max across the 32 columns (off<=16 stays within each 32-lane half)
    #pragma unroll
    for (int r = 0; r < 16; ++r) {
        float vA = rmaxA[r], vB = rmaxB[r];
        #pragma unroll
        for (int off = 1; off <= 16; off <<= 1) {
            vA = fmaxf(vA, __shfl_xor(vA, off, 64));
            vB = fmaxf(vB, __shfl_xor(vB, off, 64));
        }
        rmaxA[r] = vA; rmaxB[r] = vB;
    }
    if (l31 == 0) {
        float* dst = partmax + (size_t)by * BS + i0;
        #pragma unroll
        for (int r = 0; r < 16; ++r) {
            int row = (r & 3) + 8 * (r >> 2) + 4 * half;
            dst[row]      = rmaxA[r];
            dst[row + 32] = rmaxB[r];
        }
    }
}

// ---------------------------------------------------------------------------
// fin stage 1: 32 blocks x 256 threads; thread handles exactly one i.
// min_j d2 = a_sq[i] - 2 * max_c partmax[c][i]
// ---------------------------------------------------------------------------
__global__ __launch_bounds__(256) void fin1_kernel(
        const float* __restrict__ partmax, const float* __restrict__ a_sq,
        const float* __restrict__ pd2, float* __restrict__ bsum)
{
    __shared__ float ssum[4];
    const int t = threadIdx.x;
    const int i = blockIdx.x * 256 + t;

    float m = -3.0e38f;
    #pragma unroll
    for (int c = 0; c < NJC; ++c)
        m = fmaxf(m, partmax[c * BS + i]);
    float negd = sqrtf(fmaxf(fmaf(-2.0f, m, a_sq[i]), 0.0f));
    float posd = sqrtf(pd2[i]);
    float sum = fmaxf(posd - negd + 1.0f, 0.0f);

    #pragma unroll
    for (int off = 32; off >= 1; off >>= 1) sum += __shfl_xor(sum, off, 64);
    if ((t & 63) == 0) ssum[t >> 6] = sum;
    __syncthreads();
    if (t == 0)
        bsum[blockIdx.x] = ssum[0] + ssum[1] + ssum[2] + ssum[3];
}

// fin stage 2: one wave sums the 32 block partials.
__global__ __launch_bounds__(64) void fin2_kernel(
        const float* __restrict__ bsum, float* __restrict__ out)
{
    const int t = threadIdx.x;
    float v = (t < 32) ? bsum[t] : 0.0f;
    #pragma unroll
    for (int off = 32; off >= 1; off >>= 1) v += __shfl_xor(v, off, 64);
    if (t == 0) out[0] = v / (float)BS;
}

// ---------------------------------------------------------------------------
extern "C" void kernel_launch(void* const* d_in, const int* in_sizes, int n_in,
                              void* d_out, int out_size, void* d_ws,
                              size_t ws_size, hipStream_t stream)
{
    const float* feats = (const float*)d_in[0];

    char* ws = (char*)d_ws;
    __bf16* Apack = (__bf16*)ws;  ws += (size_t)BS * D * 2;   // 2 MB
    __bf16* Ppack = (__bf16*)ws;  ws += (size_t)BS * D * 2;   // 2 MB
    float* a_sq   = (float*)ws;   ws += (size_t)BS * 4;
    float* psn    = (float*)ws;   ws += (size_t)BS * 4;
    float* pd2    = (float*)ws;   ws += (size_t)BS * 4;
    float* partmax = (float*)ws;  ws += (size_t)NJC * BS * 4; // 512 KB
    float* bsum   = (float*)ws;   ws += 32 * 4;

    pack_kernel<<<BS / 32, 256, 0, stream>>>(feats, Apack, Ppack,
                                             a_sq, psn, pd2);
    max_kernel<<<NBLK, 512, 0, stream>>>(Apack, Ppack, psn, partmax);
    fin1_kernel<<<BS / 256, 256, 0, stream>>>(partmax, a_sq, pd2, bsum);
    fin2_kernel<<<1, 64, 0, stream>>>(bsum, (float*)d_out);
}